// Round 7
// baseline (438.500 us; speedup 1.0000x reference)
//
#include <hip/hip_runtime.h>
#include <hip/hip_fp16.h>

typedef _Float16 f16;
typedef _Float16 f16x8 __attribute__((ext_vector_type(8)));
typedef _Float16 f16x4 __attribute__((ext_vector_type(4)));
typedef float    f32x4 __attribute__((ext_vector_type(4)));
typedef unsigned long long u64;
typedef unsigned int u32;

#define HIDDEN 128
#define G3     384   // 3*HIDDEN

__device__ inline float sigm(float x) { return 1.f / (1.f + __expf(-x)); }
__device__ inline float tanh_f(float x) {
  float ax = fabsf(x);
  float e  = __expf(2.f * ax);
  float r  = 1.f - 2.f / (e + 1.f);   // overflow -> 1.0, graceful
  return x < 0.f ? -r : r;
}
__device__ inline f16x4 cvt4(float4 v) {
  return (f16x4){(f16)v.x, (f16)v.y, (f16)v.z, (f16)v.w};
}
__device__ inline f16x8 cvt8(float4 a, float4 b) {
  return (f16x8){(f16)a.x, (f16)a.y, (f16)a.z, (f16)a.w,
                 (f16)b.x, (f16)b.y, (f16)b.z, (f16)b.w};
}
__device__ inline f32x4 ld4(const float* p) { return *(const f32x4*)p; }

// ---------------- sorting pipeline ----------------

__global__ void hist_kernel(const int* __restrict__ idx, int* __restrict__ counts, int N) {
  int i = blockIdx.x * blockDim.x + threadIdx.x;
  if (i < N) atomicAdd(&counts[idx[i]], 1);
}

// fused: scan(counts)->offs, length-histogram, scan(lhist), length-ordered scatter -> order
__global__ __launch_bounds__(1024) void meta_kernel(const int* __restrict__ counts,
                                                    int* __restrict__ offs,
                                                    int* __restrict__ order, int dim) {
  __shared__ int wsum[16], wpre[16];
  __shared__ int lhist[512], loffs[512], lcur[512];
  const int tid = threadIdx.x, lane = tid & 63, wid = tid >> 6;
  for (int i = tid; i < 512; i += 1024) { lhist[i] = 0; lcur[i] = 0; }
  __syncthreads();
  // phase 1: exclusive scan counts -> offs (16 per thread) + length binning
  const int base_i = tid * 16;
  int loc[16];
  int s = 0;
#pragma unroll
  for (int u = 0; u < 16; u++) {
    int i = base_i + u;
    int x = (i < dim) ? counts[i] : 0;
    loc[u] = s; s += x;
    if (i < dim) atomicAdd(&lhist[511 - min(x, 511)], 1);
  }
  int inc = s;
#pragma unroll
  for (int d = 1; d < 64; d <<= 1) { int v = __shfl_up(inc, d, 64); if (lane >= d) inc += v; }
  if (lane == 63) wsum[wid] = inc;
  __syncthreads();
  if (wid == 0 && lane < 16) {
    int v = wsum[lane], p = v;
#pragma unroll
    for (int d = 1; d < 16; d <<= 1) { int q = __shfl_up(p, d, 16); if (lane >= d) p += q; }
    wpre[lane] = p - v;
  }
  __syncthreads();
  const int excl = wpre[wid] + inc - s;
#pragma unroll
  for (int u = 0; u < 16; u++) {
    int i = base_i + u;
    if (i < dim) offs[i] = excl + loc[u];
  }
  if (tid == 1023) offs[dim] = excl + s;
  __syncthreads();
  // phase 2: exclusive scan of lhist (512) in wave 0, 8 per lane
  if (wid == 0) {
    int l8[8]; int ss = 0;
#pragma unroll
    for (int u = 0; u < 8; u++) { l8[u] = ss; ss += lhist[lane * 8 + u]; }
    int inc2 = ss;
#pragma unroll
    for (int d = 1; d < 64; d <<= 1) { int v = __shfl_up(inc2, d, 64); if (lane >= d) inc2 += v; }
    const int e2 = inc2 - ss;
#pragma unroll
    for (int u = 0; u < 8; u++) loffs[lane * 8 + u] = e2 + l8[u];
  }
  __syncthreads();
  // phase 3: scatter group ids in descending-length order
#pragma unroll
  for (int u = 0; u < 16; u++) {
    int g = base_i + u;
    if (g < dim) {
      int b = 511 - min(counts[g], 511);
      int p = loffs[b] + atomicAdd(&lcur[b], 1);
      order[p] = g;
    }
  }
}

__global__ void scatter_kernel(const float* __restrict__ t, const int* __restrict__ idx,
                               const int* __restrict__ off, int* __restrict__ cursor,
                               u64* __restrict__ keys, int* __restrict__ pos2g, int N) {
  int i = blockIdx.x * blockDim.x + threadIdx.x;
  if (i >= N) return;
  int g = idx[i];
  int p = off[g] + atomicAdd(&cursor[g], 1);
  // t in [0,1): positive-float bits are order-preserving as uint; tie-break by i
  keys[p] = ((u64)__float_as_uint(t[i]) << 32) | (u32)i;
  pos2g[p] = g;
}

// parallel rank-select: each message counts smaller keys within its group
__global__ void rank_kernel(const u64* __restrict__ keys, const int* __restrict__ pos2g,
                            const int* __restrict__ off, const int* __restrict__ cnt,
                            u64* __restrict__ keys2, int N) {
  int p = blockIdx.x * blockDim.x + threadIdx.x;
  if (p >= N) return;
  int g = pos2g[p];
  int s = off[g], m = cnt[g];
  u64 k = keys[p];
  int r = 0;
  for (int q = 0; q < m; q++) r += (keys[s + q] < k);
  keys2[s + r] = k;
}

// ---------------- persistent fused GRU recurrence v5 ----------------
// 512 blocks (2/CU pinned) x 512 threads / 8 waves; batches of 16 chains pulled from a
// global atomic queue (order[] is length-descending -> LPT). Weights in registers ONCE
// per block. Per step: stage current msg rows (f32->f16) into swizzled double-buffered
// LDS; wave q computes gate rows [16q,16q+16) of r,z,n as 4 f32 MFMA accumulator chains;
// one barrier per step. Key for step st+1 register-rotated (loaded one step early);
// msg load issued at the top of the step body. MLP fused as per-batch epilogue.

__global__ __launch_bounds__(512, 4) void recur5(
    const float* __restrict__ msg, const u64* __restrict__ keys,
    const int* __restrict__ off, const int* __restrict__ cnt,
    const float* __restrict__ W_ih, const float* __restrict__ W_hh,
    const float* __restrict__ b_ih, const float* __restrict__ b_hh,
    const float* __restrict__ W_mlp, const float* __restrict__ b_mlp,
    const int* __restrict__ order, float* __restrict__ out,
    int dim, int nbatch, int* __restrict__ qctr) {
  __shared__ __align__(16) f16 hB[2][16 * 128];   // h state, [c][k] XOR-swizzled
  __shared__ __align__(16) f16 mB[2][16 * 128];   // current msg, same layout
  __shared__ int sArr[16], mArr[16];
  __shared__ int nextb;
  const int tid = threadIdx.x;
  const int q = tid >> 6, lane = tid & 63;
  const int c = lane & 15, hi = lane >> 4;   // chain / row-quarter
  const int ct = tid >> 5;                   // staging chain (0..15), 32 threads each
  const int j4 = (tid & 31) * 4;             // staging feature offset (f32 granularity)

  // ---- weight A-frags into registers ONCE: part p (r,z,n), k-tile kt ----
  f16x8 Ai[3][4], Ah[3][4];
#pragma unroll
  for (int p = 0; p < 3; p++)
#pragma unroll
    for (int kt = 0; kt < 4; kt++) {
      const size_t ro = (size_t)(p * 128 + q * 16 + c) * 128 + kt * 32 + hi * 8;
      Ai[p][kt] = cvt8(*(const float4*)(W_ih + ro), *(const float4*)(W_ih + ro + 4));
      Ah[p][kt] = cvt8(*(const float4*)(W_hh + ro), *(const float4*)(W_hh + ro + 4));
    }
  const int rb = q * 16 + hi * 4;
  const f32x4 bR  = ld4(b_ih + rb)       + ld4(b_hh + rb);
  const f32x4 bZ  = ld4(b_ih + 128 + rb) + ld4(b_hh + 128 + rb);
  const f32x4 bNi = ld4(b_ih + 256 + rb);
  const f32x4 bNh = ld4(b_hh + 256 + rb);
  const u32* keysLo = (const u32*)keys;

  while (true) {
    if (tid == 0) nextb = atomicAdd(qctr, 1);
    __syncthreads();
    const int b = nextb;
    __syncthreads();
    if (b >= nbatch) break;

    // ---- chain metadata for this batch ----
    const int oidx = b * 16 + c;
    const bool valid = (oidx < dim);
    const int g = valid ? order[oidx] : 0;
    const int m = valid ? cnt[g] : 0;
    const int s = (valid && m > 0) ? off[g] : 0;
    if (tid < 16) { sArr[tid] = s; mArr[tid] = m; }
    int L = m;
#pragma unroll
    for (int d = 1; d < 16; d <<= 1) L = max(L, __shfl_xor(L, d, 16));

    // ---- init h = 0 ----
    float h0[4] = {0.f, 0.f, 0.f, 0.f};
    *(f16x4*)&hB[0][c * 128 + ((q ^ (c & 7)) * 16) + hi * 4] =
        (f16x4){(f16)0.f, (f16)0.f, (f16)0.f, (f16)0.f};
    __syncthreads();   // sArr/mArr + hB[0] visible

    const int sc = sArr[ct], mc = mArr[ct];
    // ---- stage msg for step 0; key for step 1 into register ----
    {
      const u32 mid0 = keysLo[2 * sc];
      const float4 v = *(const float4*)(msg + (size_t)mid0 * 128 + j4);
      const int tk = j4 >> 4;
      *(f16x4*)&mB[0][ct * 128 + ((tk ^ (ct & 7)) * 16) + (j4 & 15)] = cvt4(v);
    }
    u32 kNext = keysLo[2 * (sc + max(0, min(1, mc - 1)))];
    __syncthreads();

    for (int st = 0; st < L; ++st) {
      // issue msg load for st+1 FIRST (max MFMA cover), key for st+2 next
      const bool stg = (st + 1 < L);
      float4 v;
      if (stg) v = *(const float4*)(msg + (size_t)kNext * 128 + j4);
      u32 kNext2 = kNext;
      if (st + 2 < L) kNext2 = keysLo[2 * (sc + max(0, min(st + 2, mc - 1)))];

      // B-frags: h and msg of all 16 chains from LDS buf[st&1]
      const f16* hr = hB[st & 1];
      const f16* mr = mB[st & 1];
      f16x8 Bh[4], Bm[4];
#pragma unroll
      for (int kt = 0; kt < 4; kt++) {
        const int ad = c * 128 + (((2 * kt + (hi >> 1)) ^ (c & 7)) * 16) + (hi & 1) * 8;
        Bh[kt] = *(const f16x8*)&hr[ad];
        Bm[kt] = *(const f16x8*)&mr[ad];
      }
      // gate pre-activations: 4 independent accumulator chains, 24 MFMAs
      f32x4 Cr = bR, Cz = bZ, Cni = bNi, Cnh = bNh;
#pragma unroll
      for (int kt = 0; kt < 4; kt++) Cr  = __builtin_amdgcn_mfma_f32_16x16x32_f16(Ai[0][kt], Bm[kt], Cr, 0, 0, 0);
#pragma unroll
      for (int kt = 0; kt < 4; kt++) Cr  = __builtin_amdgcn_mfma_f32_16x16x32_f16(Ah[0][kt], Bh[kt], Cr, 0, 0, 0);
#pragma unroll
      for (int kt = 0; kt < 4; kt++) Cz  = __builtin_amdgcn_mfma_f32_16x16x32_f16(Ai[1][kt], Bm[kt], Cz, 0, 0, 0);
#pragma unroll
      for (int kt = 0; kt < 4; kt++) Cz  = __builtin_amdgcn_mfma_f32_16x16x32_f16(Ah[1][kt], Bh[kt], Cz, 0, 0, 0);
#pragma unroll
      for (int kt = 0; kt < 4; kt++) Cni = __builtin_amdgcn_mfma_f32_16x16x32_f16(Ai[2][kt], Bm[kt], Cni, 0, 0, 0);
#pragma unroll
      for (int kt = 0; kt < 4; kt++) Cnh = __builtin_amdgcn_mfma_f32_16x16x32_f16(Ah[2][kt], Bh[kt], Cnh, 0, 0, 0);
      // gates + h update (freeze finished chains)
      const bool act = (st < m);
#pragma unroll
      for (int qq = 0; qq < 4; qq++) {
        float r = sigm(Cr[qq]);
        float z = sigm(Cz[qq]);
        float n = tanh_f(Cni[qq] + r * Cnh[qq]);
        if (act) h0[qq] = (1.f - z) * n + z * h0[qq];
      }
      // write h + staged msg into buf[(st+1)&1]
      *(f16x4*)&hB[(st + 1) & 1][c * 128 + ((q ^ (c & 7)) * 16) + hi * 4] =
          (f16x4){(f16)h0[0], (f16)h0[1], (f16)h0[2], (f16)h0[3]};
      if (stg) {
        const int tk = j4 >> 4;
        *(f16x4*)&mB[(st + 1) & 1][ct * 128 + ((tk ^ (ct & 7)) * 16) + (j4 & 15)] = cvt4(v);
      }
      __syncthreads();
      kNext = kNext2;
    }

    // ---- fused MLP: out = h @ W_mlp^T + b_mlp ; empty nodes -> 0 ----
    const f16* hf = hB[L & 1];
    f16x8 Bf[4];
#pragma unroll
    for (int kt = 0; kt < 4; kt++) {
      const int ad = c * 128 + (((2 * kt + (hi >> 1)) ^ (c & 7)) * 16) + (hi & 1) * 8;
      Bf[kt] = *(const f16x8*)&hf[ad];
    }
    f32x4 o = ld4(b_mlp + q * 16 + hi * 4);
#pragma unroll
    for (int kt = 0; kt < 4; kt++) {
      const size_t wo = (size_t)(q * 16 + c) * 128 + kt * 32 + hi * 8;
      f16x8 Af = cvt8(*(const float4*)(W_mlp + wo), *(const float4*)(W_mlp + wo + 4));
      o = __builtin_amdgcn_mfma_f32_16x16x32_f16(Af, Bf[kt], o, 0, 0, 0);
    }
    if (valid) {
      const f32x4 oz = (m > 0) ? o : (f32x4){0.f, 0.f, 0.f, 0.f};
      *(f32x4*)(out + (size_t)g * 128 + q * 16 + hi * 4) = oz;
    }
    // loop-top __syncthreads protects hB[0] reuse by the next batch
  }
}

// ---------------- host ----------------

extern "C" void kernel_launch(void* const* d_in, const int* in_sizes, int n_in,
                              void* d_out, int out_size, void* d_ws, size_t ws_size,
                              hipStream_t stream) {
  const float* msg   = (const float*)d_in[0];
  const float* t     = (const float*)d_in[1];
  const int*   indx  = (const int*)d_in[2];
  const float* W_ih  = (const float*)d_in[4];
  const float* W_hh  = (const float*)d_in[5];
  const float* b_ih  = (const float*)d_in[6];
  const float* b_hh  = (const float*)d_in[7];
  const float* W_mlp = (const float*)d_in[8];
  const float* b_mlp = (const float*)d_in[9];
  float* out = (float*)d_out;
  const int N   = in_sizes[0] / 128;
  const int dim = out_size / 128;
  const int nb  = (dim + 15) / 16;

  char* ws = (char*)d_ws;
  size_t o = 0;
  auto alloc = [&](size_t b) { size_t r = o; o = (o + b + 255) & ~(size_t)255; return r; };
  u64* keys   = (u64*)(ws + alloc((size_t)N * 8));        // 1.6 MB
  u64* keys2  = (u64*)(ws + alloc((size_t)N * 8));        // 1.6 MB
  int* pos2g  = (int*)(ws + alloc((size_t)N * 4));        // 0.8 MB
  int* offs   = (int*)(ws + alloc((size_t)(dim + 1) * 4));
  int* order  = (int*)(ws + alloc((size_t)dim * 4));
  size_t meta_bytes = (size_t)(2 * dim + 64) * 4;
  char* meta  = ws + alloc(meta_bytes);
  int* counts = (int*)meta;
  int* cursor = (int*)(meta + (size_t)dim * 4);
  int* qctr   = (int*)(meta + (size_t)2 * dim * 4);

  hipMemsetAsync(meta, 0, meta_bytes, stream);

  const int gN = (N + 255) / 256;
  hist_kernel<<<gN, 256, 0, stream>>>(indx, counts, N);
  meta_kernel<<<1, 1024, 0, stream>>>(counts, offs, order, dim);
  scatter_kernel<<<gN, 256, 0, stream>>>(t, indx, offs, cursor, keys, pos2g, N);
  rank_kernel<<<gN, 256, 0, stream>>>(keys, pos2g, offs, counts, keys2, N);

  const int pgrid = min(512, nb);
  recur5<<<pgrid, 512, 0, stream>>>(msg, keys2, offs, counts, W_ih, W_hh, b_ih, b_hh,
                                    W_mlp, b_mlp, order, out, dim, nb, qctr);
}